// Round 10
// baseline (135.885 us; speedup 1.0000x reference)
//
#include <hip/hip_runtime.h>

typedef unsigned short u16;
typedef __attribute__((ext_vector_type(8))) short bf16x8;   // 8 bf16 in 4 VGPRs
typedef __attribute__((ext_vector_type(4))) float f32x4;
typedef __attribute__((ext_vector_type(4))) unsigned short u16x4;
typedef __attribute__((ext_vector_type(4))) unsigned int u32x4;

__device__ __forceinline__ u16 f2bf(float f) {
    unsigned int u = __builtin_bit_cast(unsigned int, f);
    u += 0x7fffu + ((u >> 16) & 1u);          // round-to-nearest-even
    return (u16)(u >> 16);
}

__device__ __forceinline__ float bf2f(u16 b) {
    unsigned int u = ((unsigned int)b) << 16;
    return __builtin_bit_cast(float, u);
}

__device__ __forceinline__ unsigned int cvt_pk_bf16(float lo, float hi) {
    unsigned int r;
    asm("v_cvt_pk_bf16_f32 %0, %1, %2" : "=v"(r) : "v"(lo), "v"(hi));
    return r;                                  // [15:0]=bf16(lo) [31:16]=bf16(hi)
}

__device__ __forceinline__ void gload_lds16(const u16* g, const u16* l) {
    __builtin_amdgcn_global_load_lds((const __attribute__((address_space(1))) void*)g,
                                     (__attribute__((address_space(3))) void*)l,
                                     16, 0, 0);
}

// ---------------- fp32 -> bf16 conversion ----------------
__global__ __launch_bounds__(256) void cvt_f32_bf16(const float* __restrict__ in,
                                                    u16* __restrict__ out, int n4) {
    int i = blockIdx.x * blockDim.x + threadIdx.x;
    int stride = gridDim.x * blockDim.x;
    for (; i < n4; i += stride) {
        float4 v = reinterpret_cast<const float4*>(in)[i];
        u16x4 o = { f2bf(v.x), f2bf(v.y), f2bf(v.z), f2bf(v.w) };
        reinterpret_cast<u16x4*>(out)[i] = o;
    }
}

// ---------------- bf16 GEMM: C[m,n] = sum_k A[m,k] * B[n,k] ----------------
// 128x128 tile, BK=64, 4 waves. 1D grid with bijective XCD chunking:
// blocks sharing an A-panel (same bm) land on the same XCD's L2.
template <typename OutT>
__global__ __launch_bounds__(256) void gemm_bt(const u16* __restrict__ A, const u16* __restrict__ B,
                                               OutT* __restrict__ C, int M, int N, int K) {
    __shared__ u16 ldsA[128 * 64];
    __shared__ u16 ldsB[128 * 64];
    const int tid = threadIdx.x;
    const int lane = tid & 63;
    const int wid = tid >> 6;
    const int wm = wid >> 1, wn = wid & 1;
    const int lq = lane & 15, lg = lane >> 4;

    const int nbn = N >> 7;
    const int id = blockIdx.x;
    const int idp = (id & 7) * ((int)gridDim.x >> 3) + (id >> 3);  // grid%8==0
    const int bm = (idp / nbn) * 128;
    const int bn = (idp % nbn) * 128;

    const u16* aSrc[4];
    const u16* bSrc[4];
    int dstOff[4];
#pragma unroll
    for (int j = 0; j < 4; ++j) {
        int item = j * 256 + tid;
        int row = item >> 3;
        int c16 = item & 7;
        aSrc[j] = A + (size_t)(bm + row) * K + c16 * 8;
        bSrc[j] = B + (size_t)(bn + row) * K + c16 * 8;
        dstOff[j] = (j * 256 + (tid & ~63)) * 16;
    }

    f32x4 acc[4][4] = {};
    for (int k0 = 0; k0 < K; k0 += 64) {
        if (k0) __syncthreads();
#pragma unroll
        for (int j = 0; j < 4; ++j) {
            gload_lds16(aSrc[j], (const u16*)((const char*)ldsA + dstOff[j]));
            gload_lds16(bSrc[j], (const u16*)((const char*)ldsB + dstOff[j]));
            aSrc[j] += 64;
            bSrc[j] += 64;
        }
        __syncthreads();
#pragma unroll
        for (int kk = 0; kk < 2; ++kk) {
            bf16x8 af[4], bfr[4];
#pragma unroll
            for (int m = 0; m < 4; ++m) {
                int row = wm * 64 + m * 16 + lq;
                af[m] = *(const bf16x8*)((const char*)ldsA + row * 128 + kk * 64 + lg * 16);
            }
#pragma unroll
            for (int n = 0; n < 4; ++n) {
                int row = wn * 64 + n * 16 + lq;
                bfr[n] = *(const bf16x8*)((const char*)ldsB + row * 128 + kk * 64 + lg * 16);
            }
#pragma unroll
            for (int m = 0; m < 4; ++m)
#pragma unroll
                for (int n = 0; n < 4; ++n)
                    acc[m][n] = __builtin_amdgcn_mfma_f32_16x16x32_bf16(af[m], bfr[n], acc[m][n], 0, 0, 0);
        }
    }

#pragma unroll
    for (int m = 0; m < 4; ++m) {
#pragma unroll
        for (int n = 0; n < 4; ++n) {
#pragma unroll
            for (int r = 0; r < 4; ++r) {
                int row = bm + wm * 64 + m * 16 + lg * 4 + r;
                int col = bn + wn * 64 + n * 16 + lq;
                float v = acc[m][n][r];
                if constexpr (sizeof(OutT) == 2)
                    C[(size_t)row * N + col] = (OutT)f2bf(v);
                else
                    C[(size_t)row * N + col] = (OutT)v;
            }
        }
    }
}

// ---------------- transpose V: (B,T,[v]H,hd) -> (B,H,hd,T) ----------------
__global__ __launch_bounds__(256) void transpose_v(const u16* __restrict__ qkv, u16* __restrict__ vt) {
    __shared__ u16 tile[64][72];
    const int tb = blockIdx.x * 64;
    const int bh = blockIdx.y;
    const int b = bh >> 4, h = bh & 15;
    const u16* src = qkv + ((size_t)(b * 2048 + tb)) * 3072 + 2048 + h * 64;
    const int tid = threadIdx.x;
#pragma unroll
    for (int p = 0; p < 2; ++p) {
        int item = p * 256 + tid;
        int t = item >> 3, c = item & 7;
        bf16x8 v = *(const bf16x8*)(src + (size_t)t * 3072 + c * 8);
        *(bf16x8*)(&tile[t][c * 8]) = v;
    }
    __syncthreads();
    u16* dst = vt + ((size_t)bh * 64) * 2048 + tb;
#pragma unroll
    for (int p = 0; p < 2; ++p) {
        int item = p * 256 + tid;
        int d = item >> 3, tc = item & 7;
        bf16x8 o;
#pragma unroll
        for (int j = 0; j < 8; ++j) o[j] = (short)tile[tc * 8 + j][d];
        *(bf16x8*)(dst + (size_t)d * 2048 + tc * 8) = o;
    }
}

// ---------------- flash attention, causal, hd=64, split-K flattened ----------------
// K rows are staged into LDS in bit-permuted order pi(s1s0 l1l0 r1r0)=s0 l1l0 s1 r1r0
// so each lane's S^T registers ARE the PV A-fragment (no LDS P round-trip, no shuffles):
//   lane holds P at position p=st*16+lg*4+r -> actual s=(st&1)*32+lg*8+(st>>1)*4+r
//   PV c-th MFMA slot k=lg*8+j carries actual s=c*32+k, matching V staged unpermuted.
// Softmax max/sum are s-permutation-invariant; causal mask recomputed through pi.
// LDS 32 KB -> up to 5 blocks/CU resident.
__global__ __launch_bounds__(256, 5) void fhn_attn(const u16* __restrict__ qkv, const u16* __restrict__ vt,
                                                   u16* __restrict__ attno,
                                                   u16* __restrict__ pO, float* __restrict__ pML) {
    __shared__ u16 kvbuf[2][2][64 * 64];      // [dbuf][0=K,1=V][row][chunk swizzled]  32 KB
    const int id = blockIdx.x;
    const int xcd = id & 7;
    const int u = id >> 3;                    // 0..191
    const int bh = xcd * 4 + (u & 3);
    const int unit = u >> 2;                  // 0..47, heavy first
    int qt, jb0, jb1, sidx;
    bool split;
    if (unit < 32) {
        qt = 31 - (unit >> 1);
        sidx = unit & 1;
        split = true;
        int n = qt + 1, hh = (n + 1) >> 1;
        jb0 = sidx ? hh : 0;
        jb1 = sidx ? n : hh;
    } else {
        qt = 47 - unit;
        sidx = 0;
        split = false;
        jb0 = 0;
        jb1 = qt + 1;
    }
    const int b = bh >> 4, h = bh & 15;
    const int tid = threadIdx.x;
    const int w = tid >> 6;
    const int lane = tid & 63;
    const int lq = lane & 15, lg = lane >> 4;
    const int qlo = qt * 64 + w * 16;         // wave's first q row
    const int tq = qlo + lq;                  // softmax row owned by this lane

    // Q fragments (B-operand of swapped QK^T), pre-scaled by log2(e)/sqrt(64)
    bf16x8 qf[2];
    {
        const u16* qrow = qkv + ((size_t)(b * 2048 + tq)) * 3072 + h * 64;
        qf[0] = *(const bf16x8*)(qrow + lg * 8);
        qf[1] = *(const bf16x8*)(qrow + 32 + lg * 8);
#pragma unroll
        for (int kk = 0; kk < 2; ++kk)
#pragma unroll
            for (int j = 0; j < 8; ++j)
                qf[kk][j] = (short)f2bf(bf2f((u16)qf[kk][j]) * 0.1803368801f);
    }

    // staging: 64 rows x 8 chunks(16B) per tile; 2 chunks/thread for K and V each.
    // LDS[row][c] = G[pi(row)][c ^ (row&7)] for K (row-permuted source),
    // LDS[row][c] = G[row][c ^ (row&7)] for V. Linear LDS dest (m104 rule).
    const int it0 = tid, it1 = 256 + tid;
    const int r0 = it0 >> 3, g0 = (it0 & 7) ^ (r0 & 7);
    const int r1 = it1 >> 3, g1 = (it1 & 7) ^ (r1 & 7);
    const int pr0 = (((r0 >> 4) & 1) << 5) | ((r0 & 12) << 1) | (((r0 >> 5) & 1) << 2) | (r0 & 3);
    const int pr1 = (((r1 >> 4) & 1) << 5) | ((r1 & 12) << 1) | (((r1 >> 5) & 1) << 2) | (r1 & 3);
    const u16* kS0 = qkv + ((size_t)(b * 2048 + jb0 * 64 + pr0)) * 3072 + 1024 + h * 64 + g0 * 8;
    const u16* kS1 = qkv + ((size_t)(b * 2048 + jb0 * 64 + pr1)) * 3072 + 1024 + h * 64 + g1 * 8;
    const u16* vS0 = vt + ((size_t)bh * 64 + r0) * 2048 + jb0 * 64 + g0 * 8;
    const u16* vS1 = vt + ((size_t)bh * 64 + r1) * 2048 + jb0 * 64 + g1 * 8;
    const int d0 = (it0 & ~63) * 8;           // wave-uniform LDS element base
    const int d1 = (it1 & ~63) * 8;

#define STAGE(buf)                                            \
    do {                                                      \
        gload_lds16(kS0, &kvbuf[buf][0][d0]);                 \
        gload_lds16(kS1, &kvbuf[buf][0][d1]);                 \
        gload_lds16(vS0, &kvbuf[buf][1][d0]);                 \
        gload_lds16(vS1, &kvbuf[buf][1][d1]);                 \
        kS0 += 64 * 3072; kS1 += 64 * 3072;                   \
        vS0 += 64; vS1 += 64;                                 \
    } while (0)

    float m_run = -1e30f, l_run = 0.f;
    f32x4 oacc[4] = {};
    int cur = 0;

    STAGE(0);                                  // prefetch first kv block

    for (int jb = jb0; jb < jb1; ++jb) {
        // current tile's loads (issued last iter) are the only outstanding vmem
        asm volatile("s_waitcnt vmcnt(0)" ::: "memory");
        __builtin_amdgcn_s_barrier();          // also: everyone finished reading cur^1
        __builtin_amdgcn_sched_barrier(0);
        if (jb + 1 < jb1) STAGE(cur ^ 1);      // overwrite freed buffer; lands under compute

        const u16* kb = kvbuf[cur][0];
        const u16* vb = kvbuf[cur][1];

        // ---- QK^T (swapped): S^T = K_perm * Q^T, scores already in log2 units
        float p[4][4];
        __builtin_amdgcn_s_setprio(1);
#pragma unroll
        for (int st = 0; st < 4; ++st) {
            int row = st * 16 + lq;
            f32x4 sacc = {};
            sacc = __builtin_amdgcn_mfma_f32_16x16x32_bf16(
                *(const bf16x8*)(kb + row * 64 + ((lg ^ (row & 7)) * 8)), qf[0], sacc, 0, 0, 0);
            sacc = __builtin_amdgcn_mfma_f32_16x16x32_bf16(
                *(const bf16x8*)(kb + row * 64 + (((4 + lg) ^ (row & 7)) * 8)), qf[1], sacc, 0, 0, 0);
#pragma unroll
            for (int r = 0; r < 4; ++r) p[st][r] = sacc[r];
        }
        __builtin_amdgcn_s_setprio(0);

        // V fragments now: ds_read latency hides under the softmax VALU chain
        bf16x8 vf[2][4];
#pragma unroll
        for (int c = 0; c < 2; ++c)
#pragma unroll
            for (int nd = 0; nd < 4; ++nd) {
                int row = nd * 16 + lq;
                vf[c][nd] = *(const bf16x8*)(vb + row * 64 + (((c * 4 + lg) ^ (row & 7)) * 8));
            }

        if (jb == qt) {                        // mask diagonal tile; actual s via pi
#pragma unroll
            for (int st = 0; st < 4; ++st)
#pragma unroll
                for (int r = 0; r < 4; ++r) {
                    int s = jb * 64 + ((st & 1) << 5) + (lg << 3) + ((st >> 1) << 2) + r;
                    if (s > tq) p[st][r] = -1e30f;
                }
        }

        // tree max (depth 4 instead of 16-deep serial chain)
        float mst[4];
#pragma unroll
        for (int st = 0; st < 4; ++st)
            mst[st] = fmaxf(fmaxf(p[st][0], p[st][1]), fmaxf(p[st][2], p[st][3]));
        float mloc = fmaxf(fmaxf(mst[0], mst[1]), fmaxf(mst[2], mst[3]));
        mloc = fmaxf(mloc, __shfl_xor(mloc, 16));
        mloc = fmaxf(mloc, __shfl_xor(mloc, 32));

        // defer-max: skip O-rescale while row max grows by <= 8 (log2 domain)
        if (!__all(mloc - m_run <= 8.0f)) {
            float mnew = fmaxf(m_run, mloc);
            float scp = exp2f(m_run - mnew);
            m_run = mnew;
            l_run *= scp;
            float f0 = __shfl(scp, lg * 4 + 0);
            float f1 = __shfl(scp, lg * 4 + 1);
            float f2_ = __shfl(scp, lg * 4 + 2);
            float f3 = __shfl(scp, lg * 4 + 3);
#pragma unroll
            for (int nd = 0; nd < 4; ++nd) {
                oacc[nd][0] *= f0; oacc[nd][1] *= f1;
                oacc[nd][2] *= f2_; oacc[nd][3] *= f3;
            }
        }

        // exp + tree sum (permutation-invariant)
        float lst[4];
#pragma unroll
        for (int st = 0; st < 4; ++st) {
#pragma unroll
            for (int r = 0; r < 4; ++r)
                p[st][r] = exp2f(p[st][r] - m_run);
            lst[st] = (p[st][0] + p[st][1]) + (p[st][2] + p[st][3]);
        }
        float lloc = (lst[0] + lst[1]) + (lst[2] + lst[3]);
        lloc += __shfl_xor(lloc, 16);
        lloc += __shfl_xor(lloc, 32);
        l_run += lloc;

        // ---- PV: O += P * V. A-fragment built in-register (pi made layouts match):
        //   pa_c = [p[c][0..3], p[c+2][0..3]] packed to bf16
        __builtin_amdgcn_s_setprio(1);
#pragma unroll
        for (int c = 0; c < 2; ++c) {
            u32x4 pw = { cvt_pk_bf16(p[c][0], p[c][1]),
                         cvt_pk_bf16(p[c][2], p[c][3]),
                         cvt_pk_bf16(p[c + 2][0], p[c + 2][1]),
                         cvt_pk_bf16(p[c + 2][2], p[c + 2][3]) };
            bf16x8 pa = __builtin_bit_cast(bf16x8, pw);
#pragma unroll
            for (int nd = 0; nd < 4; ++nd)
                oacc[nd] = __builtin_amdgcn_mfma_f32_16x16x32_bf16(pa, vf[c][nd], oacc[nd], 0, 0, 0);
        }
        __builtin_amdgcn_s_setprio(0);

        cur ^= 1;
    }
#undef STAGE

    if (split) {
        // unnormalized partial: O (bf16) + per-row m,l (f32)
        const int pidx = ((((bh << 4) | (qt - 16)) << 1) + sidx);
        u16* obase = pO + (size_t)pidx * 4096;
#pragma unroll
        for (int nd = 0; nd < 4; ++nd)
#pragma unroll
            for (int r = 0; r < 4; ++r) {
                int rt = w * 16 + lg * 4 + r;
                obase[rt * 64 + nd * 16 + lq] = f2bf(oacc[nd][r]);
            }
        if (lg == 0) {
            pML[pidx * 128 + w * 16 + lq] = m_run;
            pML[pidx * 128 + 64 + w * 16 + lq] = l_run;
        }
    } else {
        // direct normalized output (per output row q = lg*4+r)
        float li0 = 1.f / __shfl(l_run, lg * 4 + 0);
        float li1 = 1.f / __shfl(l_run, lg * 4 + 1);
        float li2 = 1.f / __shfl(l_run, lg * 4 + 2);
        float li3 = 1.f / __shfl(l_run, lg * 4 + 3);
#pragma unroll
        for (int nd = 0; nd < 4; ++nd) {
#pragma unroll
            for (int r = 0; r < 4; ++r) {
                int trow = qlo + lg * 4 + r;
                float li = (r == 0) ? li0 : (r == 1) ? li1 : (r == 2) ? li2 : li3;
                attno[((size_t)(b * 2048 + trow)) * 1024 + h * 64 + nd * 16 + lq] =
                    f2bf(oacc[nd][r] * li);
            }
        }
    }
}

// ---------------- merge two kv-split partials (log2-domain flash merge) ----------------
__global__ __launch_bounds__(256) void attn_merge(const u16* __restrict__ pO, const float* __restrict__ pML,
                                                  u16* __restrict__ attno) {
    const int tilei = blockIdx.x;             // 0..511 = (bh<<4)|q16
    const int bh = tilei >> 4, q16 = tilei & 15;
    const int qt = 16 + q16;
    const int b = bh >> 4, h = bh & 15;
    const int p0 = tilei * 2, p1 = p0 + 1;
    const int t = threadIdx.x;
    const int rt = t >> 2;                    // row in tile 0..63
    const int c0 = (t & 3) * 16;              // col base

    float m0 = pML[p0 * 128 + rt], l0 = pML[p0 * 128 + 64 + rt];
    float m1 = pML[p1 * 128 + rt], l1 = pML[p1 * 128 + 64 + rt];
    float M = fmaxf(m0, m1);
    float a0 = exp2f(m0 - M), a1 = exp2f(m1 - M);
    float inv = 1.f / (l0 * a0 + l1 * a1);
    a0 *= inv; a1 *= inv;

    const u16* O0 = pO + (size_t)p0 * 4096 + rt * 64 + c0;
    const u16* O1 = pO + (size_t)p1 * 4096 + rt * 64 + c0;
    u16* dst = attno + ((size_t)(b * 2048 + qt * 64 + rt)) * 1024 + h * 64 + c0;
#pragma unroll
    for (int half = 0; half < 2; ++half) {
        bf16x8 v0 = *(const bf16x8*)(O0 + half * 8);
        bf16x8 v1 = *(const bf16x8*)(O1 + half * 8);
        bf16x8 o;
#pragma unroll
        for (int j = 0; j < 8; ++j)
            o[j] = (short)f2bf(bf2f((u16)v0[j]) * a0 + bf2f((u16)v1[j]) * a1);
        *(bf16x8*)(dst + half * 8) = o;
    }
}

extern "C" void kernel_launch(void* const* d_in, const int* in_sizes, int n_in,
                              void* d_out, int out_size, void* d_ws, size_t ws_size,
                              hipStream_t stream) {
    const float* x    = (const float*)d_in[0];   // (2,2048,1024)
    const float* Wqkv = (const float*)d_in[1];   // (3072,1024)
    const float* Wout = (const float*)d_in[2];   // (1024,1024)
    float* out = (float*)d_out;

    char* ws = (char*)d_ws;
    u16* xb    = (u16*)(ws + 0);           //  8,388,608 B  (reused as pO after qkv GEMM)
    u16* wqkvb = (u16*)(ws + 8388608);     //  6,291,456 B  (reused as pML after qkv GEMM)
    u16* woutb = (u16*)(ws + 14680064);    //  2,097,152 B
    u16* qkvb  = (u16*)(ws + 16777216);    // 25,165,824 B
    u16* vtb   = (u16*)(ws + 41943040);    //  8,388,608 B
    u16* attno = (u16*)(ws + 50331648);    //  8,388,608 B  (end 58,720,256)
    u16* pO    = xb;                       // 1024 partials x 8192 B = 8,388,608 B
    float* pML = (float*)wqkvb;            // 1024 partials x 512 B  =   524,288 B

    cvt_f32_bf16<<<2048, 256, 0, stream>>>(x, xb, 4194304 / 4);
    cvt_f32_bf16<<<2048, 256, 0, stream>>>(Wqkv, wqkvb, 3145728 / 4);
    cvt_f32_bf16<<<1024, 256, 0, stream>>>(Wout, woutb, 1048576 / 4);

    gemm_bt<u16><<<768, 256, 0, stream>>>(xb, wqkvb, qkvb, 4096, 3072, 1024);

    transpose_v<<<dim3(32, 32), 256, 0, stream>>>(qkvb, vtb);

    fhn_attn<<<1536, 256, 0, stream>>>(qkvb, vtb, attno, pO, pML);

    attn_merge<<<512, 256, 0, stream>>>(pO, pML, attno);

    gemm_bt<float><<<256, 256, 0, stream>>>(attno, woutb, out, 4096, 1024, 1024);
}

// Round 11
// 111.882 us; speedup vs baseline: 1.2145x; 1.2145x over previous
//
#include <hip/hip_runtime.h>

typedef unsigned short u16;
typedef __attribute__((ext_vector_type(8))) short bf16x8;   // 8 bf16 in 4 VGPRs
typedef __attribute__((ext_vector_type(4))) float f32x4;
typedef __attribute__((ext_vector_type(4))) unsigned short u16x4;
typedef __attribute__((ext_vector_type(4))) unsigned int u32x4;

__device__ __forceinline__ u16 f2bf(float f) {
    unsigned int u = __builtin_bit_cast(unsigned int, f);
    u += 0x7fffu + ((u >> 16) & 1u);          // round-to-nearest-even
    return (u16)(u >> 16);
}

__device__ __forceinline__ float bf2f(u16 b) {
    unsigned int u = ((unsigned int)b) << 16;
    return __builtin_bit_cast(float, u);
}

__device__ __forceinline__ unsigned int cvt_pk_bf16(float lo, float hi) {
    unsigned int r;
    asm("v_cvt_pk_bf16_f32 %0, %1, %2" : "=v"(r) : "v"(lo), "v"(hi));
    return r;                                  // [15:0]=bf16(lo) [31:16]=bf16(hi)
}

__device__ __forceinline__ void gload_lds16(const u16* g, const u16* l) {
    __builtin_amdgcn_global_load_lds((const __attribute__((address_space(1))) void*)g,
                                     (__attribute__((address_space(3))) void*)l,
                                     16, 0, 0);
}

// ---------------- fp32 -> bf16 conversion, 3 buffers in one launch ----------------
__global__ __launch_bounds__(256) void cvt3_f32_bf16(const float* __restrict__ a, u16* __restrict__ ab, int na4,
                                                     const float* __restrict__ b, u16* __restrict__ bb, int nb4,
                                                     const float* __restrict__ c, u16* __restrict__ cb, int nc4) {
    const int stride = gridDim.x * blockDim.x;
    int i0 = blockIdx.x * blockDim.x + threadIdx.x;
    for (int i = i0; i < na4; i += stride) {
        float4 v = reinterpret_cast<const float4*>(a)[i];
        u16x4 o = { f2bf(v.x), f2bf(v.y), f2bf(v.z), f2bf(v.w) };
        reinterpret_cast<u16x4*>(ab)[i] = o;
    }
    for (int i = i0; i < nb4; i += stride) {
        float4 v = reinterpret_cast<const float4*>(b)[i];
        u16x4 o = { f2bf(v.x), f2bf(v.y), f2bf(v.z), f2bf(v.w) };
        reinterpret_cast<u16x4*>(bb)[i] = o;
    }
    for (int i = i0; i < nc4; i += stride) {
        float4 v = reinterpret_cast<const float4*>(c)[i];
        u16x4 o = { f2bf(v.x), f2bf(v.y), f2bf(v.z), f2bf(v.w) };
        reinterpret_cast<u16x4*>(cb)[i] = o;
    }
}

// ---------------- bf16 GEMM: C[m,n] = sum_k A[m,k] * B[n,k] ----------------
// BMxBN tile, BK=64, 4 waves (2x2), per-wave (BM/2)x(BN/2) via 16x16x32 frags.
// 1D grid with bijective XCD chunking: blocks sharing an A-panel land on one XCD's L2.
template <int BM, int BN, typename OutT>
__global__ __launch_bounds__(256) void gemm_bt(const u16* __restrict__ A, const u16* __restrict__ B,
                                               OutT* __restrict__ C, int M, int N, int K) {
    __shared__ u16 ldsA[BM * 64];
    __shared__ u16 ldsB[BN * 64];
    constexpr int RA = BM * 8 / 256;          // staging rounds for A tile
    constexpr int RB = BN * 8 / 256;
    constexpr int MF = BM / 32;               // 16-row frags per wave (M)
    constexpr int NF = BN / 32;
    const int tid = threadIdx.x;
    const int lane = tid & 63;
    const int wid = tid >> 6;
    const int wm = wid >> 1, wn = wid & 1;
    const int lq = lane & 15, lg = lane >> 4;

    const int nbn = N / BN;
    const int id = blockIdx.x;
    const int idp = (id & 7) * ((int)gridDim.x >> 3) + (id >> 3);  // grid%8==0
    const int bm = (idp / nbn) * BM;
    const int bn = (idp % nbn) * BN;

    const u16* aSrc[RA];
    const u16* bSrc[RB];
    int dstOffA[RA], dstOffB[RB];
#pragma unroll
    for (int j = 0; j < RA; ++j) {
        int item = j * 256 + tid;
        aSrc[j] = A + (size_t)(bm + (item >> 3)) * K + (item & 7) * 8;
        dstOffA[j] = (j * 256 + (tid & ~63)) * 16;
    }
#pragma unroll
    for (int j = 0; j < RB; ++j) {
        int item = j * 256 + tid;
        bSrc[j] = B + (size_t)(bn + (item >> 3)) * K + (item & 7) * 8;
        dstOffB[j] = (j * 256 + (tid & ~63)) * 16;
    }

    f32x4 acc[MF][NF] = {};
    for (int k0 = 0; k0 < K; k0 += 64) {
        if (k0) __syncthreads();
#pragma unroll
        for (int j = 0; j < RA; ++j) {
            gload_lds16(aSrc[j], (const u16*)((const char*)ldsA + dstOffA[j]));
            aSrc[j] += 64;
        }
#pragma unroll
        for (int j = 0; j < RB; ++j) {
            gload_lds16(bSrc[j], (const u16*)((const char*)ldsB + dstOffB[j]));
            bSrc[j] += 64;
        }
        __syncthreads();
#pragma unroll
        for (int kk = 0; kk < 2; ++kk) {
            bf16x8 af[MF], bfr[NF];
#pragma unroll
            for (int m = 0; m < MF; ++m) {
                int row = wm * (BM / 2) + m * 16 + lq;
                af[m] = *(const bf16x8*)((const char*)ldsA + row * 128 + kk * 64 + lg * 16);
            }
#pragma unroll
            for (int n = 0; n < NF; ++n) {
                int row = wn * (BN / 2) + n * 16 + lq;
                bfr[n] = *(const bf16x8*)((const char*)ldsB + row * 128 + kk * 64 + lg * 16);
            }
#pragma unroll
            for (int m = 0; m < MF; ++m)
#pragma unroll
                for (int n = 0; n < NF; ++n)
                    acc[m][n] = __builtin_amdgcn_mfma_f32_16x16x32_bf16(af[m], bfr[n], acc[m][n], 0, 0, 0);
        }
    }

#pragma unroll
    for (int m = 0; m < MF; ++m) {
#pragma unroll
        for (int n = 0; n < NF; ++n) {
#pragma unroll
            for (int r = 0; r < 4; ++r) {
                int row = bm + wm * (BM / 2) + m * 16 + lg * 4 + r;
                int col = bn + wn * (BN / 2) + n * 16 + lq;
                float v = acc[m][n][r];
                if constexpr (sizeof(OutT) == 2)
                    C[(size_t)row * N + col] = (OutT)f2bf(v);
                else
                    C[(size_t)row * N + col] = (OutT)v;
            }
        }
    }
}

// ---------------- transpose V: (B,T,[v]H,hd) -> (B,H,hd,T) ----------------
__global__ __launch_bounds__(256) void transpose_v(const u16* __restrict__ qkv, u16* __restrict__ vt) {
    __shared__ u16 tile[64][72];
    const int tb = blockIdx.x * 64;
    const int bh = blockIdx.y;
    const int b = bh >> 4, h = bh & 15;
    const u16* src = qkv + ((size_t)(b * 2048 + tb)) * 3072 + 2048 + h * 64;
    const int tid = threadIdx.x;
#pragma unroll
    for (int p = 0; p < 2; ++p) {
        int item = p * 256 + tid;
        int t = item >> 3, c = item & 7;
        bf16x8 v = *(const bf16x8*)(src + (size_t)t * 3072 + c * 8);
        *(bf16x8*)(&tile[t][c * 8]) = v;
    }
    __syncthreads();
    u16* dst = vt + ((size_t)bh * 64) * 2048 + tb;
#pragma unroll
    for (int p = 0; p < 2; ++p) {
        int item = p * 256 + tid;
        int d = item >> 3, tc = item & 7;
        bf16x8 o;
#pragma unroll
        for (int j = 0; j < 8; ++j) o[j] = (short)tile[tc * 8 + j][d];
        *(bf16x8*)(dst + (size_t)d * 2048 + tc * 8) = o;
    }
}

// ---------------- flash attention, causal, hd=64, split-K flattened ----------------
// K rows staged in bit-permuted order pi(s1s0 l1l0 r1r0)=s0 l1l0 s1 r1r0 so each
// lane's S^T registers ARE the PV A-fragment (no LDS P round-trip). Softmax stats are
// s-permutation-invariant; causal mask recomputed through pi. l-reduction deferred to
// the epilogue (per-lane lacc, scaled on rescale events). LDS 32 KB, 4 blocks/CU.
__global__ __launch_bounds__(256, 4) void fhn_attn(const u16* __restrict__ qkv, const u16* __restrict__ vt,
                                                   u16* __restrict__ attno,
                                                   u16* __restrict__ pO, float* __restrict__ pML) {
    __shared__ u16 kvbuf[2][2][64 * 64];      // [dbuf][0=K,1=V][row][chunk swizzled]  32 KB
    const int id = blockIdx.x;
    const int xcd = id & 7;
    const int u = id >> 3;                    // 0..191
    const int bh = xcd * 4 + (u & 3);
    const int unit = u >> 2;                  // 0..47, heavy first
    int qt, jb0, jb1, sidx;
    bool split;
    if (unit < 32) {
        qt = 31 - (unit >> 1);
        sidx = unit & 1;
        split = true;
        int n = qt + 1, hh = (n + 1) >> 1;
        jb0 = sidx ? hh : 0;
        jb1 = sidx ? n : hh;
    } else {
        qt = 47 - unit;
        sidx = 0;
        split = false;
        jb0 = 0;
        jb1 = qt + 1;
    }
    const int b = bh >> 4, h = bh & 15;
    const int tid = threadIdx.x;
    const int w = tid >> 6;
    const int lane = tid & 63;
    const int lq = lane & 15, lg = lane >> 4;
    const int qlo = qt * 64 + w * 16;         // wave's first q row
    const int tq = qlo + lq;                  // softmax row owned by this lane

    // Q fragments (B-operand of swapped QK^T), pre-scaled by log2(e)/sqrt(64)
    bf16x8 qf[2];
    {
        const u16* qrow = qkv + ((size_t)(b * 2048 + tq)) * 3072 + h * 64;
        qf[0] = *(const bf16x8*)(qrow + lg * 8);
        qf[1] = *(const bf16x8*)(qrow + 32 + lg * 8);
#pragma unroll
        for (int kk = 0; kk < 2; ++kk)
#pragma unroll
            for (int j = 0; j < 8; ++j)
                qf[kk][j] = (short)f2bf(bf2f((u16)qf[kk][j]) * 0.1803368801f);
    }

    // staging: 64 rows x 8 chunks(16B) per tile; 2 chunks/thread for K and V each.
    // LDS[row][c] = G[pi(row)][c ^ (row&7)] for K (row-permuted source),
    // LDS[row][c] = G[row][c ^ (row&7)] for V. Linear LDS dest (m104 rule).
    const int it0 = tid, it1 = 256 + tid;
    const int r0 = it0 >> 3, g0 = (it0 & 7) ^ (r0 & 7);
    const int r1 = it1 >> 3, g1 = (it1 & 7) ^ (r1 & 7);
    const int pr0 = (((r0 >> 4) & 1) << 5) | ((r0 & 12) << 1) | (((r0 >> 5) & 1) << 2) | (r0 & 3);
    const int pr1 = (((r1 >> 4) & 1) << 5) | ((r1 & 12) << 1) | (((r1 >> 5) & 1) << 2) | (r1 & 3);
    const u16* kS0 = qkv + ((size_t)(b * 2048 + jb0 * 64 + pr0)) * 3072 + 1024 + h * 64 + g0 * 8;
    const u16* kS1 = qkv + ((size_t)(b * 2048 + jb0 * 64 + pr1)) * 3072 + 1024 + h * 64 + g1 * 8;
    const u16* vS0 = vt + ((size_t)bh * 64 + r0) * 2048 + jb0 * 64 + g0 * 8;
    const u16* vS1 = vt + ((size_t)bh * 64 + r1) * 2048 + jb0 * 64 + g1 * 8;
    const int d0 = (it0 & ~63) * 8;           // wave-uniform LDS element base
    const int d1 = (it1 & ~63) * 8;

#define STAGE(buf)                                            \
    do {                                                      \
        gload_lds16(kS0, &kvbuf[buf][0][d0]);                 \
        gload_lds16(kS1, &kvbuf[buf][0][d1]);                 \
        gload_lds16(vS0, &kvbuf[buf][1][d0]);                 \
        gload_lds16(vS1, &kvbuf[buf][1][d1]);                 \
        kS0 += 64 * 3072; kS1 += 64 * 3072;                   \
        vS0 += 64; vS1 += 64;                                 \
    } while (0)

    float m_run = -1e30f;
    f32x4 lacc = { 0.f, 0.f, 0.f, 0.f };      // deferred l partials (one per st)
    f32x4 oacc[4] = {};
    int cur = 0;

    STAGE(0);                                  // prefetch first kv block

    for (int jb = jb0; jb < jb1; ++jb) {
        // current tile's loads (issued last iter) are the only outstanding vmem
        asm volatile("s_waitcnt vmcnt(0)" ::: "memory");
        __builtin_amdgcn_s_barrier();          // also: everyone finished reading cur^1
        __builtin_amdgcn_sched_barrier(0);
        if (jb + 1 < jb1) STAGE(cur ^ 1);      // overwrite freed buffer; lands under compute

        const u16* kb = kvbuf[cur][0];
        const u16* vb = kvbuf[cur][1];

        // ---- QK^T (swapped): S^T = K_perm * Q^T, scores already in log2 units
        float p[4][4];
        __builtin_amdgcn_s_setprio(1);
#pragma unroll
        for (int st = 0; st < 4; ++st) {
            int row = st * 16 + lq;
            f32x4 sacc = {};
            sacc = __builtin_amdgcn_mfma_f32_16x16x32_bf16(
                *(const bf16x8*)(kb + row * 64 + ((lg ^ (row & 7)) * 8)), qf[0], sacc, 0, 0, 0);
            sacc = __builtin_amdgcn_mfma_f32_16x16x32_bf16(
                *(const bf16x8*)(kb + row * 64 + (((4 + lg) ^ (row & 7)) * 8)), qf[1], sacc, 0, 0, 0);
#pragma unroll
            for (int r = 0; r < 4; ++r) p[st][r] = sacc[r];
        }
        __builtin_amdgcn_s_setprio(0);

        // V fragments now: ds_read latency hides under the softmax VALU chain
        bf16x8 vf[2][4];
#pragma unroll
        for (int c = 0; c < 2; ++c)
#pragma unroll
            for (int nd = 0; nd < 4; ++nd) {
                int row = nd * 16 + lq;
                vf[c][nd] = *(const bf16x8*)(vb + row * 64 + (((c * 4 + lg) ^ (row & 7)) * 8));
            }

        if (jb == qt) {                        // mask diagonal tile; actual s via pi
#pragma unroll
            for (int st = 0; st < 4; ++st)
#pragma unroll
                for (int r = 0; r < 4; ++r) {
                    int s = jb * 64 + ((st & 1) << 5) + (lg << 3) + ((st >> 1) << 2) + r;
                    if (s > tq) p[st][r] = -1e30f;
                }
        }

        // tree max (depth 4)
        float mst[4];
#pragma unroll
        for (int st = 0; st < 4; ++st)
            mst[st] = fmaxf(fmaxf(p[st][0], p[st][1]), fmaxf(p[st][2], p[st][3]));
        float mloc = fmaxf(fmaxf(mst[0], mst[1]), fmaxf(mst[2], mst[3]));
        mloc = fmaxf(mloc, __shfl_xor(mloc, 16));
        mloc = fmaxf(mloc, __shfl_xor(mloc, 32));

        // defer-max: skip O-rescale while row max grows by <= 8 (log2 domain)
        if (!__all(mloc - m_run <= 8.0f)) {
            float mnew = fmaxf(m_run, mloc);
            float scp = exp2f(m_run - mnew);
            m_run = mnew;
#pragma unroll
            for (int st = 0; st < 4; ++st) lacc[st] *= scp;
            float f0 = __shfl(scp, lg * 4 + 0);
            float f1 = __shfl(scp, lg * 4 + 1);
            float f2_ = __shfl(scp, lg * 4 + 2);
            float f3 = __shfl(scp, lg * 4 + 3);
#pragma unroll
            for (int nd = 0; nd < 4; ++nd) {
                oacc[nd][0] *= f0; oacc[nd][1] *= f1;
                oacc[nd][2] *= f2_; oacc[nd][3] *= f3;
            }
        }

        // exp + per-lane l accumulation (cross-lane reduce deferred to epilogue)
#pragma unroll
        for (int st = 0; st < 4; ++st) {
#pragma unroll
            for (int r = 0; r < 4; ++r)
                p[st][r] = exp2f(p[st][r] - m_run);
            lacc[st] += (p[st][0] + p[st][1]) + (p[st][2] + p[st][3]);
        }

        // ---- PV: O += P * V. A-fragment built in-register (pi made layouts match):
        //   pa_c = [p[c][0..3], p[c+2][0..3]] packed to bf16
        __builtin_amdgcn_s_setprio(1);
#pragma unroll
        for (int c = 0; c < 2; ++c) {
            u32x4 pw = { cvt_pk_bf16(p[c][0], p[c][1]),
                         cvt_pk_bf16(p[c][2], p[c][3]),
                         cvt_pk_bf16(p[c + 2][0], p[c + 2][1]),
                         cvt_pk_bf16(p[c + 2][2], p[c + 2][3]) };
            bf16x8 pa = __builtin_bit_cast(bf16x8, pw);
#pragma unroll
            for (int nd = 0; nd < 4; ++nd)
                oacc[nd] = __builtin_amdgcn_mfma_f32_16x16x32_bf16(pa, vf[c][nd], oacc[nd], 0, 0, 0);
        }
        __builtin_amdgcn_s_setprio(0);

        cur ^= 1;
    }
#undef STAGE

    // final cross-lane l reduction (row lives on 4 lanes sharing lq)
    float l_run = (lacc[0] + lacc[1]) + (lacc[2] + lacc[3]);
    l_run += __shfl_xor(l_run, 16);
    l_run += __shfl_xor(l_run, 32);

    if (split) {
        // unnormalized partial: O (bf16) + per-row m,l (f32)
        const int pidx = ((((bh << 4) | (qt - 16)) << 1) + sidx);
        u16* obase = pO + (size_t)pidx * 4096;
#pragma unroll
        for (int nd = 0; nd < 4; ++nd)
#pragma unroll
            for (int r = 0; r < 4; ++r) {
                int rt = w * 16 + lg * 4 + r;
                obase[rt * 64 + nd * 16 + lq] = f2bf(oacc[nd][r]);
            }
        if (lg == 0) {
            pML[pidx * 128 + w * 16 + lq] = m_run;
            pML[pidx * 128 + 64 + w * 16 + lq] = l_run;
        }
    } else {
        // direct normalized output (per output row q = lg*4+r)
        float li0 = 1.f / __shfl(l_run, lg * 4 + 0);
        float li1 = 1.f / __shfl(l_run, lg * 4 + 1);
        float li2 = 1.f / __shfl(l_run, lg * 4 + 2);
        float li3 = 1.f / __shfl(l_run, lg * 4 + 3);
#pragma unroll
        for (int nd = 0; nd < 4; ++nd) {
#pragma unroll
            for (int r = 0; r < 4; ++r) {
                int trow = qlo + lg * 4 + r;
                float li = (r == 0) ? li0 : (r == 1) ? li1 : (r == 2) ? li2 : li3;
                attno[((size_t)(b * 2048 + trow)) * 1024 + h * 64 + nd * 16 + lq] =
                    f2bf(oacc[nd][r] * li);
            }
        }
    }
}

// ---------------- merge two kv-split partials (log2-domain flash merge) ----------------
__global__ __launch_bounds__(256) void attn_merge(const u16* __restrict__ pO, const float* __restrict__ pML,
                                                  u16* __restrict__ attno) {
    const int tilei = blockIdx.x;             // 0..511 = (bh<<4)|q16
    const int bh = tilei >> 4, q16 = tilei & 15;
    const int qt = 16 + q16;
    const int b = bh >> 4, h = bh & 15;
    const int p0 = tilei * 2, p1 = p0 + 1;
    const int t = threadIdx.x;
    const int rt = t >> 2;                    // row in tile 0..63
    const int c0 = (t & 3) * 16;              // col base

    float m0 = pML[p0 * 128 + rt], l0 = pML[p0 * 128 + 64 + rt];
    float m1 = pML[p1 * 128 + rt], l1 = pML[p1 * 128 + 64 + rt];
    float M = fmaxf(m0, m1);
    float a0 = exp2f(m0 - M), a1 = exp2f(m1 - M);
    float inv = 1.f / (l0 * a0 + l1 * a1);
    a0 *= inv; a1 *= inv;

    const u16* O0 = pO + (size_t)p0 * 4096 + rt * 64 + c0;
    const u16* O1 = pO + (size_t)p1 * 4096 + rt * 64 + c0;
    u16* dst = attno + ((size_t)(b * 2048 + qt * 64 + rt)) * 1024 + h * 64 + c0;
#pragma unroll
    for (int half = 0; half < 2; ++half) {
        bf16x8 v0 = *(const bf16x8*)(O0 + half * 8);
        bf16x8 v1 = *(const bf16x8*)(O1 + half * 8);
        bf16x8 o;
#pragma unroll
        for (int j = 0; j < 8; ++j)
            o[j] = (short)f2bf(bf2f((u16)v0[j]) * a0 + bf2f((u16)v1[j]) * a1);
        *(bf16x8*)(dst + half * 8) = o;
    }
}

extern "C" void kernel_launch(void* const* d_in, const int* in_sizes, int n_in,
                              void* d_out, int out_size, void* d_ws, size_t ws_size,
                              hipStream_t stream) {
    const float* x    = (const float*)d_in[0];   // (2,2048,1024)
    const float* Wqkv = (const float*)d_in[1];   // (3072,1024)
    const float* Wout = (const float*)d_in[2];   // (1024,1024)
    float* out = (float*)d_out;

    char* ws = (char*)d_ws;
    u16* xb    = (u16*)(ws + 0);           //  8,388,608 B  (reused as pO after qkv GEMM)
    u16* wqkvb = (u16*)(ws + 8388608);     //  6,291,456 B  (reused as pML after qkv GEMM)
    u16* woutb = (u16*)(ws + 14680064);    //  2,097,152 B
    u16* qkvb  = (u16*)(ws + 16777216);    // 25,165,824 B
    u16* vtb   = (u16*)(ws + 41943040);    //  8,388,608 B
    u16* attno = (u16*)(ws + 50331648);    //  8,388,608 B  (end 58,720,256)
    u16* pO    = xb;                       // 1024 partials x 8192 B = 8,388,608 B
    float* pML = (float*)wqkvb;            // 1024 partials x 512 B  =   524,288 B

    cvt3_f32_bf16<<<2048, 256, 0, stream>>>(x, xb, 4194304 / 4,
                                            Wqkv, wqkvb, 3145728 / 4,
                                            Wout, woutb, 1048576 / 4);

    gemm_bt<128, 128, u16><<<768, 256, 0, stream>>>(xb, wqkvb, qkvb, 4096, 3072, 1024);

    transpose_v<<<dim3(32, 32), 256, 0, stream>>>(qkvb, vtb);

    fhn_attn<<<1536, 256, 0, stream>>>(qkvb, vtb, attno, pO, pML);

    attn_merge<<<512, 256, 0, stream>>>(pO, pML, attno);

    gemm_bt<64, 128, float><<<512, 256, 0, stream>>>(attno, woutb, out, 4096, 1024, 1024);
}

// Round 13
// 111.802 us; speedup vs baseline: 1.2154x; 1.0007x over previous
//
#include <hip/hip_runtime.h>

typedef unsigned short u16;
typedef __attribute__((ext_vector_type(8))) short bf16x8;   // 8 bf16 in 4 VGPRs
typedef __attribute__((ext_vector_type(4))) float f32x4;
typedef __attribute__((ext_vector_type(4))) unsigned short u16x4;
typedef __attribute__((ext_vector_type(4))) unsigned int u32x4;

__device__ __forceinline__ u16 f2bf(float f) {
    unsigned int u = __builtin_bit_cast(unsigned int, f);
    u += 0x7fffu + ((u >> 16) & 1u);          // round-to-nearest-even
    return (u16)(u >> 16);
}

__device__ __forceinline__ float bf2f(u16 b) {
    unsigned int u = ((unsigned int)b) << 16;
    return __builtin_bit_cast(float, u);
}

__device__ __forceinline__ unsigned int cvt_pk_bf16(float lo, float hi) {
    unsigned int r;
    asm("v_cvt_pk_bf16_f32 %0, %1, %2" : "=v"(r) : "v"(lo), "v"(hi));
    return r;                                  // [15:0]=bf16(lo) [31:16]=bf16(hi)
}

__device__ __forceinline__ void gload_lds16(const u16* g, const u16* l) {
    __builtin_amdgcn_global_load_lds((const __attribute__((address_space(1))) void*)g,
                                     (__attribute__((address_space(3))) void*)l,
                                     16, 0, 0);
}

// ---------------- fp32 -> bf16 conversion, 3 buffers in one launch ----------------
__global__ __launch_bounds__(256) void cvt3_f32_bf16(const float* __restrict__ a, u16* __restrict__ ab, int na4,
                                                     const float* __restrict__ b, u16* __restrict__ bb, int nb4,
                                                     const float* __restrict__ c, u16* __restrict__ cb, int nc4) {
    const int stride = gridDim.x * blockDim.x;
    int i0 = blockIdx.x * blockDim.x + threadIdx.x;
    for (int i = i0; i < na4; i += stride) {
        float4 v = reinterpret_cast<const float4*>(a)[i];
        u16x4 o = { f2bf(v.x), f2bf(v.y), f2bf(v.z), f2bf(v.w) };
        reinterpret_cast<u16x4*>(ab)[i] = o;
    }
    for (int i = i0; i < nb4; i += stride) {
        float4 v = reinterpret_cast<const float4*>(b)[i];
        u16x4 o = { f2bf(v.x), f2bf(v.y), f2bf(v.z), f2bf(v.w) };
        reinterpret_cast<u16x4*>(bb)[i] = o;
    }
    for (int i = i0; i < nc4; i += stride) {
        float4 v = reinterpret_cast<const float4*>(c)[i];
        u16x4 o = { f2bf(v.x), f2bf(v.y), f2bf(v.z), f2bf(v.w) };
        reinterpret_cast<u16x4*>(cb)[i] = o;
    }
}

// ---------------- bf16 GEMM: C[m,n] = sum_k A[m,k] * B[n,k] ----------------
// BMxBN tile, BK=64, 4 waves (2x2), per-wave (BM/2)x(BN/2) via 16x16x32 frags.
// 1D grid with bijective XCD chunking: blocks sharing an A-panel land on one XCD's L2.
template <int BM, int BN, typename OutT>
__global__ __launch_bounds__(256) void gemm_bt(const u16* __restrict__ A, const u16* __restrict__ B,
                                               OutT* __restrict__ C, int M, int N, int K) {
    __shared__ u16 ldsA[BM * 64];
    __shared__ u16 ldsB[BN * 64];
    constexpr int RA = BM * 8 / 256;          // staging rounds for A tile
    constexpr int RB = BN * 8 / 256;
    constexpr int MF = BM / 32;               // 16-row frags per wave (M)
    constexpr int NF = BN / 32;
    const int tid = threadIdx.x;
    const int lane = tid & 63;
    const int wid = tid >> 6;
    const int wm = wid >> 1, wn = wid & 1;
    const int lq = lane & 15, lg = lane >> 4;

    const int nbn = N / BN;
    const int id = blockIdx.x;
    const int idp = (id & 7) * ((int)gridDim.x >> 3) + (id >> 3);  // grid%8==0
    const int bm = (idp / nbn) * BM;
    const int bn = (idp % nbn) * BN;

    const u16* aSrc[RA];
    const u16* bSrc[RB];
    int dstOffA[RA], dstOffB[RB];
#pragma unroll
    for (int j = 0; j < RA; ++j) {
        int item = j * 256 + tid;
        aSrc[j] = A + (size_t)(bm + (item >> 3)) * K + (item & 7) * 8;
        dstOffA[j] = (j * 256 + (tid & ~63)) * 16;
    }
#pragma unroll
    for (int j = 0; j < RB; ++j) {
        int item = j * 256 + tid;
        bSrc[j] = B + (size_t)(bn + (item >> 3)) * K + (item & 7) * 8;
        dstOffB[j] = (j * 256 + (tid & ~63)) * 16;
    }

    f32x4 acc[MF][NF] = {};
    for (int k0 = 0; k0 < K; k0 += 64) {
        if (k0) __syncthreads();
#pragma unroll
        for (int j = 0; j < RA; ++j) {
            gload_lds16(aSrc[j], (const u16*)((const char*)ldsA + dstOffA[j]));
            aSrc[j] += 64;
        }
#pragma unroll
        for (int j = 0; j < RB; ++j) {
            gload_lds16(bSrc[j], (const u16*)((const char*)ldsB + dstOffB[j]));
            bSrc[j] += 64;
        }
        __syncthreads();
#pragma unroll
        for (int kk = 0; kk < 2; ++kk) {
            bf16x8 af[MF], bfr[NF];
#pragma unroll
            for (int m = 0; m < MF; ++m) {
                int row = wm * (BM / 2) + m * 16 + lq;
                af[m] = *(const bf16x8*)((const char*)ldsA + row * 128 + kk * 64 + lg * 16);
            }
#pragma unroll
            for (int n = 0; n < NF; ++n) {
                int row = wn * (BN / 2) + n * 16 + lq;
                bfr[n] = *(const bf16x8*)((const char*)ldsB + row * 128 + kk * 64 + lg * 16);
            }
#pragma unroll
            for (int m = 0; m < MF; ++m)
#pragma unroll
                for (int n = 0; n < NF; ++n)
                    acc[m][n] = __builtin_amdgcn_mfma_f32_16x16x32_bf16(af[m], bfr[n], acc[m][n], 0, 0, 0);
        }
    }

#pragma unroll
    for (int m = 0; m < MF; ++m) {
#pragma unroll
        for (int n = 0; n < NF; ++n) {
#pragma unroll
            for (int r = 0; r < 4; ++r) {
                int row = bm + wm * (BM / 2) + m * 16 + lg * 4 + r;
                int col = bn + wn * (BN / 2) + n * 16 + lq;
                float v = acc[m][n][r];
                if constexpr (sizeof(OutT) == 2)
                    C[(size_t)row * N + col] = (OutT)f2bf(v);
                else
                    C[(size_t)row * N + col] = (OutT)v;
            }
        }
    }
}

// ---------------- transpose V: (B,T,[v]H,hd) -> (B,H,hd,T) ----------------
__global__ __launch_bounds__(256) void transpose_v(const u16* __restrict__ qkv, u16* __restrict__ vt) {
    __shared__ u16 tile[64][72];
    const int tb = blockIdx.x * 64;
    const int bh = blockIdx.y;
    const int b = bh >> 4, h = bh & 15;
    const u16* src = qkv + ((size_t)(b * 2048 + tb)) * 3072 + 2048 + h * 64;
    const int tid = threadIdx.x;
#pragma unroll
    for (int p = 0; p < 2; ++p) {
        int item = p * 256 + tid;
        int t = item >> 3, c = item & 7;
        bf16x8 v = *(const bf16x8*)(src + (size_t)t * 3072 + c * 8);
        *(bf16x8*)(&tile[t][c * 8]) = v;
    }
    __syncthreads();
    u16* dst = vt + ((size_t)bh * 64) * 2048 + tb;
#pragma unroll
    for (int p = 0; p < 2; ++p) {
        int item = p * 256 + tid;
        int d = item >> 3, tc = item & 7;
        bf16x8 o;
#pragma unroll
        for (int j = 0; j < 8; ++j) o[j] = (short)tile[tc * 8 + j][d];
        *(bf16x8*)(dst + (size_t)d * 2048 + tc * 8) = o;
    }
}

// ---------------- flash attention, causal, hd=64, split-K flattened ----------------
// K rows staged in bit-permuted order pi(s1s0 l1l0 r1r0)=s0 l1l0 s1 r1r0 so each
// lane's S^T registers ARE the PV A-fragment (no LDS P round-trip). Softmax stats are
// s-permutation-invariant; causal mask recomputed through pi. l-reduction deferred to
// the epilogue (per-lane lacc, scaled on rescale events). LDS 32 KB, 4 blocks/CU.
__global__ __launch_bounds__(256, 4) void fhn_attn(const u16* __restrict__ qkv, const u16* __restrict__ vt,
                                                   u16* __restrict__ attno,
                                                   u16* __restrict__ pO, float* __restrict__ pML) {
    __shared__ u16 kvbuf[2][2][64 * 64];      // [dbuf][0=K,1=V][row][chunk swizzled]  32 KB
    const int id = blockIdx.x;
    const int xcd = id & 7;
    const int u = id >> 3;                    // 0..191
    const int bh = xcd * 4 + (u & 3);
    const int unit = u >> 2;                  // 0..47, heavy first
    int qt, jb0, jb1, sidx;
    bool split;
    if (unit < 32) {
        qt = 31 - (unit >> 1);
        sidx = unit & 1;
        split = true;
        int n = qt + 1, hh = (n + 1) >> 1;
        jb0 = sidx ? hh : 0;
        jb1 = sidx ? n : hh;
    } else {
        qt = 47 - unit;
        sidx = 0;
        split = false;
        jb0 = 0;
        jb1 = qt + 1;
    }
    const int b = bh >> 4, h = bh & 15;
    const int tid = threadIdx.x;
    const int w = tid >> 6;
    const int lane = tid & 63;
    const int lq = lane & 15, lg = lane >> 4;
    const int qlo = qt * 64 + w * 16;         // wave's first q row
    const int tq = qlo + lq;                  // softmax row owned by this lane

    // Q fragments (B-operand of swapped QK^T), pre-scaled by log2(e)/sqrt(64)
    bf16x8 qf[2];
    {
        const u16* qrow = qkv + ((size_t)(b * 2048 + tq)) * 3072 + h * 64;
        qf[0] = *(const bf16x8*)(qrow + lg * 8);
        qf[1] = *(const bf16x8*)(qrow + 32 + lg * 8);
#pragma unroll
        for (int kk = 0; kk < 2; ++kk)
#pragma unroll
            for (int j = 0; j < 8; ++j)
                qf[kk][j] = (short)f2bf(bf2f((u16)qf[kk][j]) * 0.1803368801f);
    }

    // staging: 64 rows x 8 chunks(16B) per tile; 2 chunks/thread for K and V each.
    // LDS[row][c] = G[pi(row)][c ^ (row&7)] for K (row-permuted source),
    // LDS[row][c] = G[row][c ^ (row&7)] for V. Linear LDS dest (m104 rule).
    const int it0 = tid, it1 = 256 + tid;
    const int r0 = it0 >> 3, g0 = (it0 & 7) ^ (r0 & 7);
    const int r1 = it1 >> 3, g1 = (it1 & 7) ^ (r1 & 7);
    const int pr0 = (((r0 >> 4) & 1) << 5) | ((r0 & 12) << 1) | (((r0 >> 5) & 1) << 2) | (r0 & 3);
    const int pr1 = (((r1 >> 4) & 1) << 5) | ((r1 & 12) << 1) | (((r1 >> 5) & 1) << 2) | (r1 & 3);
    const u16* kS0 = qkv + ((size_t)(b * 2048 + jb0 * 64 + pr0)) * 3072 + 1024 + h * 64 + g0 * 8;
    const u16* kS1 = qkv + ((size_t)(b * 2048 + jb0 * 64 + pr1)) * 3072 + 1024 + h * 64 + g1 * 8;
    const u16* vS0 = vt + ((size_t)bh * 64 + r0) * 2048 + jb0 * 64 + g0 * 8;
    const u16* vS1 = vt + ((size_t)bh * 64 + r1) * 2048 + jb0 * 64 + g1 * 8;
    const int d0 = (it0 & ~63) * 8;           // wave-uniform LDS element base
    const int d1 = (it1 & ~63) * 8;

#define STAGE(buf)                                            \
    do {                                                      \
        gload_lds16(kS0, &kvbuf[buf][0][d0]);                 \
        gload_lds16(kS1, &kvbuf[buf][0][d1]);                 \
        gload_lds16(vS0, &kvbuf[buf][1][d0]);                 \
        gload_lds16(vS1, &kvbuf[buf][1][d1]);                 \
        kS0 += 64 * 3072; kS1 += 64 * 3072;                   \
        vS0 += 64; vS1 += 64;                                 \
    } while (0)

    float m_run = -1e30f;
    f32x4 lacc = { 0.f, 0.f, 0.f, 0.f };      // deferred l partials (one per st)
    f32x4 oacc[4] = {};
    int cur = 0;

    STAGE(0);                                  // prefetch first kv block

    for (int jb = jb0; jb < jb1; ++jb) {
        // current tile's loads (issued last iter) are the only outstanding vmem
        asm volatile("s_waitcnt vmcnt(0)" ::: "memory");
        __builtin_amdgcn_s_barrier();          // also: everyone finished reading cur^1
        __builtin_amdgcn_sched_barrier(0);
        if (jb + 1 < jb1) STAGE(cur ^ 1);      // overwrite freed buffer; lands under compute

        const u16* kb = kvbuf[cur][0];
        const u16* vb = kvbuf[cur][1];

        // ---- QK^T (swapped): S^T = K_perm * Q^T, scores already in log2 units
        float p[4][4];
        __builtin_amdgcn_s_setprio(1);
#pragma unroll
        for (int st = 0; st < 4; ++st) {
            int row = st * 16 + lq;
            f32x4 sacc = {};
            sacc = __builtin_amdgcn_mfma_f32_16x16x32_bf16(
                *(const bf16x8*)(kb + row * 64 + ((lg ^ (row & 7)) * 8)), qf[0], sacc, 0, 0, 0);
            sacc = __builtin_amdgcn_mfma_f32_16x16x32_bf16(
                *(const bf16x8*)(kb + row * 64 + (((4 + lg) ^ (row & 7)) * 8)), qf[1], sacc, 0, 0, 0);
#pragma unroll
            for (int r = 0; r < 4; ++r) p[st][r] = sacc[r];
        }
        __builtin_amdgcn_s_setprio(0);

        // V fragments now: ds_read latency hides under the softmax VALU chain
        bf16x8 vf[2][4];
#pragma unroll
        for (int c = 0; c < 2; ++c)
#pragma unroll
            for (int nd = 0; nd < 4; ++nd) {
                int row = nd * 16 + lq;
                vf[c][nd] = *(const bf16x8*)(vb + row * 64 + (((c * 4 + lg) ^ (row & 7)) * 8));
            }

        if (jb == qt) {                        // mask diagonal tile; actual s via pi
#pragma unroll
            for (int st = 0; st < 4; ++st)
#pragma unroll
                for (int r = 0; r < 4; ++r) {
                    int s = jb * 64 + ((st & 1) << 5) + (lg << 3) + ((st >> 1) << 2) + r;
                    if (s > tq) p[st][r] = -1e30f;
                }
        }

        // tree max (depth 4)
        float mst[4];
#pragma unroll
        for (int st = 0; st < 4; ++st)
            mst[st] = fmaxf(fmaxf(p[st][0], p[st][1]), fmaxf(p[st][2], p[st][3]));
        float mloc = fmaxf(fmaxf(mst[0], mst[1]), fmaxf(mst[2], mst[3]));
        mloc = fmaxf(mloc, __shfl_xor(mloc, 16));
        mloc = fmaxf(mloc, __shfl_xor(mloc, 32));

        // defer-max: skip O-rescale while row max grows by <= 8 (log2 domain)
        if (!__all(mloc - m_run <= 8.0f)) {
            float mnew = fmaxf(m_run, mloc);
            float scp = exp2f(m_run - mnew);
            m_run = mnew;
#pragma unroll
            for (int st = 0; st < 4; ++st) lacc[st] *= scp;
            float f0 = __shfl(scp, lg * 4 + 0);
            float f1 = __shfl(scp, lg * 4 + 1);
            float f2_ = __shfl(scp, lg * 4 + 2);
            float f3 = __shfl(scp, lg * 4 + 3);
#pragma unroll
            for (int nd = 0; nd < 4; ++nd) {
                oacc[nd][0] *= f0; oacc[nd][1] *= f1;
                oacc[nd][2] *= f2_; oacc[nd][3] *= f3;
            }
        }

        // exp + per-lane l accumulation (cross-lane reduce deferred to epilogue)
#pragma unroll
        for (int st = 0; st < 4; ++st) {
#pragma unroll
            for (int r = 0; r < 4; ++r)
                p[st][r] = exp2f(p[st][r] - m_run);
            lacc[st] += (p[st][0] + p[st][1]) + (p[st][2] + p[st][3]);
        }

        // ---- PV: O += P * V. A-fragment built in-register (pi made layouts match):
        //   pa_c = [p[c][0..3], p[c+2][0..3]] packed to bf16
        __builtin_amdgcn_s_setprio(1);
#pragma unroll
        for (int c = 0; c < 2; ++c) {
            u32x4 pw = { cvt_pk_bf16(p[c][0], p[c][1]),
                         cvt_pk_bf16(p[c][2], p[c][3]),
                         cvt_pk_bf16(p[c + 2][0], p[c + 2][1]),
                         cvt_pk_bf16(p[c + 2][2], p[c + 2][3]) };
            bf16x8 pa = __builtin_bit_cast(bf16x8, pw);
#pragma unroll
            for (int nd = 0; nd < 4; ++nd)
                oacc[nd] = __builtin_amdgcn_mfma_f32_16x16x32_bf16(pa, vf[c][nd], oacc[nd], 0, 0, 0);
        }
        __builtin_amdgcn_s_setprio(0);

        cur ^= 1;
    }
#undef STAGE

    // final cross-lane l reduction (row lives on 4 lanes sharing lq)
    float l_run = (lacc[0] + lacc[1]) + (lacc[2] + lacc[3]);
    l_run += __shfl_xor(l_run, 16);
    l_run += __shfl_xor(l_run, 32);

    if (split) {
        // unnormalized partial: O (bf16) + per-row m,l (f32)
        const int pidx = ((((bh << 4) | (qt - 16)) << 1) + sidx);
        u16* obase = pO + (size_t)pidx * 4096;
#pragma unroll
        for (int nd = 0; nd < 4; ++nd)
#pragma unroll
            for (int r = 0; r < 4; ++r) {
                int rt = w * 16 + lg * 4 + r;
                obase[rt * 64 + nd * 16 + lq] = f2bf(oacc[nd][r]);
            }
        if (lg == 0) {
            pML[pidx * 128 + w * 16 + lq] = m_run;
            pML[pidx * 128 + 64 + w * 16 + lq] = l_run;
        }
    } else {
        // direct normalized output (per output row q = lg*4+r)
        float li0 = 1.f / __shfl(l_run, lg * 4 + 0);
        float li1 = 1.f / __shfl(l_run, lg * 4 + 1);
        float li2 = 1.f / __shfl(l_run, lg * 4 + 2);
        float li3 = 1.f / __shfl(l_run, lg * 4 + 3);
#pragma unroll
        for (int nd = 0; nd < 4; ++nd) {
#pragma unroll
            for (int r = 0; r < 4; ++r) {
                int trow = qlo + lg * 4 + r;
                float li = (r == 0) ? li0 : (r == 1) ? li1 : (r == 2) ? li2 : li3;
                attno[((size_t)(b * 2048 + trow)) * 1024 + h * 64 + nd * 16 + lq] =
                    f2bf(oacc[nd][r] * li);
            }
        }
    }
}

// ---------------- merge two kv-split partials (log2-domain flash merge) ----------------
__global__ __launch_bounds__(256) void attn_merge(const u16* __restrict__ pO, const float* __restrict__ pML,
                                                  u16* __restrict__ attno) {
    const int tilei = blockIdx.x;             // 0..511 = (bh<<4)|q16
    const int bh = tilei >> 4, q16 = tilei & 15;
    const int qt = 16 + q16;
    const int b = bh >> 4, h = bh & 15;
    const int p0 = tilei * 2, p1 = p0 + 1;
    const int t = threadIdx.x;
    const int rt = t >> 2;                    // row in tile 0..63
    const int c0 = (t & 3) * 16;              // col base

    float m0 = pML[p0 * 128 + rt], l0 = pML[p0 * 128 + 64 + rt];
    float m1 = pML[p1 * 128 + rt], l1 = pML[p1 * 128 + 64 + rt];
    float M = fmaxf(m0, m1);
    float a0 = exp2f(m0 - M), a1 = exp2f(m1 - M);
    float inv = 1.f / (l0 * a0 + l1 * a1);
    a0 *= inv; a1 *= inv;

    const u16* O0 = pO + (size_t)p0 * 4096 + rt * 64 + c0;
    const u16* O1 = pO + (size_t)p1 * 4096 + rt * 64 + c0;
    u16* dst = attno + ((size_t)(b * 2048 + qt * 64 + rt)) * 1024 + h * 64 + c0;
#pragma unroll
    for (int half = 0; half < 2; ++half) {
        bf16x8 v0 = *(const bf16x8*)(O0 + half * 8);
        bf16x8 v1 = *(const bf16x8*)(O1 + half * 8);
        bf16x8 o;
#pragma unroll
        for (int j = 0; j < 8; ++j)
            o[j] = (short)f2bf(bf2f((u16)v0[j]) * a0 + bf2f((u16)v1[j]) * a1);
        *(bf16x8*)(dst + half * 8) = o;
    }
}

extern "C" void kernel_launch(void* const* d_in, const int* in_sizes, int n_in,
                              void* d_out, int out_size, void* d_ws, size_t ws_size,
                              hipStream_t stream) {
    const float* x    = (const float*)d_in[0];   // (2,2048,1024)
    const float* Wqkv = (const float*)d_in[1];   // (3072,1024)
    const float* Wout = (const float*)d_in[2];   // (1024,1024)
    float* out = (float*)d_out;

    char* ws = (char*)d_ws;
    u16* xb    = (u16*)(ws + 0);           //  8,388,608 B  (reused as pO after qkv GEMM)
    u16* wqkvb = (u16*)(ws + 8388608);     //  6,291,456 B  (reused as pML after qkv GEMM)
    u16* woutb = (u16*)(ws + 14680064);    //  2,097,152 B
    u16* qkvb  = (u16*)(ws + 16777216);    // 25,165,824 B
    u16* vtb   = (u16*)(ws + 41943040);    //  8,388,608 B
    u16* attno = (u16*)(ws + 50331648);    //  8,388,608 B  (end 58,720,256)
    u16* pO    = xb;                       // 1024 partials x 8192 B = 8,388,608 B
    float* pML = (float*)wqkvb;            // 1024 partials x 512 B  =   524,288 B

    cvt3_f32_bf16<<<2048, 256, 0, stream>>>(x, xb, 4194304 / 4,
                                            Wqkv, wqkvb, 3145728 / 4,
                                            Wout, woutb, 1048576 / 4);

    gemm_bt<128, 128, u16><<<768, 256, 0, stream>>>(xb, wqkvb, qkvb, 4096, 3072, 1024);

    transpose_v<<<dim3(32, 32), 256, 0, stream>>>(qkvb, vtb);

    fhn_attn<<<1536, 256, 0, stream>>>(qkvb, vtb, attno, pO, pML);

    attn_merge<<<512, 256, 0, stream>>>(pO, pML, attno);

    gemm_bt<64, 128, float><<<512, 256, 0, stream>>>(attno, woutb, out, 4096, 1024, 1024);
}